// Round 11
// baseline (327.729 us; speedup 1.0000x reference)
//
#include <hip/hip_runtime.h>
#include <hip/hip_bf16.h>
#include <math.h>

// ---------------------------------------------------------------------------
// ResidualBlock (PyG GMMConv/MoNet + BN train + ELU), v11.
//   v10 persistent fused gather+MFMA, software-pipelined:
//   - double-buffered LDS A-tile; ONE barrier per tile. Per tile: gather t,
//     write sA[p], MFMA of tile t-1 from sA[1-p], barrier, flip. Early waves
//     do the previous tile's MFMA while slow waves still gather.
//   - grid = 1536 (6 blocks/CU, LDS-limited residency) -> no late-start tail.
//   - prep_xb folded into binfill_k; GCUR+STATS share one memset.
// ---------------------------------------------------------------------------

#define ELU(v) ((v) > 0.f ? (v) : (__expf(v) - 1.f))

using short8  = __attribute__((ext_vector_type(8))) short;
using floatx4 = __attribute__((ext_vector_type(4))) float;

__device__ inline ushort f2bf(float f) {
    __hip_bfloat16 h = __float2bfloat16(f);
    return *reinterpret_cast<ushort*>(&h);
}
__device__ inline float bflo(unsigned u) { return __uint_as_float(u << 16); }
__device__ inline float bfhi(unsigned u) { return __uint_as_float(u & 0xffff0000u); }
__device__ inline unsigned pack_bf2(float lo, float hi) {
    return ((unsigned)f2bf(hi) << 16) | (unsigned)f2bf(lo);
}

// ---- pass-B gather-source cast: XB = bf16(elu(bn1(out1))) -----------------
__global__ __launch_bounds__(256) void prep_hxb(
    const float* __restrict__ out1, const float* __restrict__ coef,
    unsigned* __restrict__ XB, int N)
{
    const int idx = blockIdx.x * blockDim.x + threadIdx.x;
    if (idx >= N * 16) return;
    const int l = idx & 15;
    const float2 p = ((const float2*)out1)[idx];
    const int c0 = 2 * l, c1 = 2 * l + 1;
    float v0 = p.x * coef[c0] + coef[32 + c0];
    float v1 = p.y * coef[c1] + coef[32 + c1];
    v0 = ELU(v0); v1 = ELU(v1);
    XB[idx] = pack_bf2(v0, v1);
}

// ---- CSR build, level 1: LDS-binned partition + fused XB cast -------------
#define CH 4096
__global__ __launch_bounds__(256) void binfill_k(
    const int* __restrict__ ei, const float* __restrict__ attr,
    int* __restrict__ gcur, unsigned long long* __restrict__ pay0,
    const float* __restrict__ x, unsigned* __restrict__ XB, int nxb,
    int E, int NB, int CAPc)
{
    __shared__ unsigned long long srec[CH];     // 32 KB
    __shared__ unsigned char sbin[CH];          // 4 KB
    __shared__ int cnt[256], offs[256], wcur[256], gbase[256], sc[256];

    const int t = threadIdx.x;
    const int e0 = blockIdx.x * CH;
    const int nrec = min(CH, E - e0);

    // fused pass-A XB cast (independent of partition work)
    for (int i = t; i < CH; i += 256) {
        const int idx = e0 + i;
        if (idx < nxb) {
            const float2 p = ((const float2*)x)[idx];
            XB[idx] = pack_bf2(p.x, p.y);
        }
    }

    cnt[t] = 0;
    __syncthreads();

    unsigned long long rec[16];
    int bin[16];
#pragma unroll
    for (int r = 0; r < 16; ++r) {
        const int e = e0 + r * 256 + t;
        bin[r] = -1;
        if (e < E) {
            const int s = ei[e], d = ei[E + e];
            const float a0 = attr[(size_t)e * 3 + 0];
            const float a1 = attr[(size_t)e * 3 + 1];
            const float a2 = attr[(size_t)e * 3 + 2];
            const unsigned q0 = (unsigned)min(max((int)(a0 * 4096.f), 0), 4095);
            const unsigned q1 = (unsigned)min(max((int)(a1 * 4096.f), 0), 4095);
            const unsigned q2 = (unsigned)min(max((int)(a2 * 4096.f), 0), 4095);
            rec[r] = (unsigned long long)(unsigned)s
                   | ((unsigned long long)(d & 511) << 17)
                   | ((unsigned long long)q0 << 26)
                   | ((unsigned long long)q1 << 38)
                   | ((unsigned long long)q2 << 50);
            bin[r] = d >> 9;
            atomicAdd(&cnt[bin[r]], 1);
        }
    }
    __syncthreads();

    const int v = cnt[t];
    sc[t] = v;
    __syncthreads();
    for (int o = 1; o < 256; o <<= 1) {
        const int xx = (t >= o) ? sc[t - o] : 0;
        __syncthreads();
        sc[t] += xx;
        __syncthreads();
    }
    offs[t] = sc[t] - v;
    wcur[t] = sc[t] - v;
    __syncthreads();

#pragma unroll
    for (int r = 0; r < 16; ++r) {
        if (bin[r] >= 0) {
            const int pos = atomicAdd(&wcur[bin[r]], 1);
            srec[pos] = rec[r];
            sbin[pos] = (unsigned char)bin[r];
        }
    }
    __syncthreads();

    if (t < NB && cnt[t] > 0) gbase[t] = atomicAdd(&gcur[t], cnt[t]);
    __syncthreads();

    for (int i = t; i < nrec; i += 256) {
        const int b = sbin[i];
        const int idx = gbase[b] + (i - offs[b]);
        if (idx < CAPc)
            pay0[(size_t)b * CAPc + idx] = srec[i];
    }
}

// ---- CSR build, level 2: bucket base + degree count + row_ptr + scatter ---
__global__ __launch_bounds__(256) void scatter2_k(
    const unsigned long long* __restrict__ pay0, const int* __restrict__ gcur,
    int* __restrict__ row_ptr, unsigned long long* __restrict__ pay,
    int N, int CAPc, int NB)
{
    const int b = blockIdx.x;
    const int t = threadIdx.x;
    const int d0 = b << 9;
    const int nd = min(512, N - d0);

    __shared__ int cnt[512];
    __shared__ int offs[512];
    __shared__ int sscan[256];
    __shared__ int ssum[256];

    ssum[t] = (t < b && t < NB) ? gcur[t] : 0;
    for (int i = t; i < 512; i += 256) cnt[i] = 0;
    __syncthreads();
    for (int o = 128; o > 0; o >>= 1) {
        if (t < o) ssum[t] += ssum[t + o];
        __syncthreads();
    }
    const int base = ssum[0];

    const int total = min(gcur[b], CAPc);
    const unsigned long long* src = pay0 + (size_t)b * CAPc;

    for (int i = t; i < total; i += 256) {
        const int dlo = (int)((src[i] >> 17) & 511);
        atomicAdd(&cnt[dlo], 1);
    }
    __syncthreads();

    const int c0 = cnt[2 * t], c1 = cnt[2 * t + 1];
    const int pairsum = c0 + c1;
    sscan[t] = pairsum;
    __syncthreads();
    for (int o = 1; o < 256; o <<= 1) {
        const int xx = (t >= o) ? sscan[t - o] : 0;
        __syncthreads();
        sscan[t] += xx;
        __syncthreads();
    }
    const int excl = sscan[t] - pairsum;
    offs[2 * t] = excl;
    offs[2 * t + 1] = excl + c0;
    __syncthreads();
    const int btotal = sscan[255];

    for (int i = t; i < nd; i += 256) row_ptr[d0 + i] = base + offs[i];
    if (b == NB - 1 && t == 0) row_ptr[N] = base + btotal;

    for (int i = t; i < 512; i += 256) cnt[i] = offs[i];
    __syncthreads();

    for (int i = t; i < total; i += 256) {
        const unsigned long long rec = src[i];
        const int dlo = (int)((rec >> 17) & 511);
        const int p = atomicAdd(&cnt[dlo], 1);
        pay[base + p] = rec;
    }
}

// ---- fused gather + MFMA (software-pipelined, double-buffered A-tile) -----
template <bool HAS_S>
__global__ __launch_bounds__(256) void gt_k(
    const unsigned* __restrict__ XB,    // [n][16] dwords = 32 bf16 channels
    const unsigned long long* __restrict__ payload,
    const int* __restrict__ row_ptr,
    const float* __restrict__ mu_m, const float* __restrict__ sg_m,
    const float* __restrict__ mu_s, const float* __restrict__ sg_s,
    const float* __restrict__ g,        // [32][160]
    const float* __restrict__ rootm,    // [32][32]
    const float* __restrict__ bm,       // [32]
    const float* __restrict__ gss,      // [32][32] (HAS_S)
    const float* __restrict__ rootss,   // [32][32] (HAS_S)
    const float* __restrict__ bss,      // [32]     (HAS_S)
    float* __restrict__ out_m, float* __restrict__ out_s,
    float* __restrict__ stats_m, float* __restrict__ stats_s,
    int N, int ntiles)
{
    constexpr int KS = HAS_S ? 6 : 5;       // gathered slots
    constexpr int SLS = KS + 1;             // + root slot
    constexpr int STRIDE = SLS * 16 + 4;    // dwords
    constexpr float DQ = 1.0f / 4096.0f;

    __shared__ float wbuf[16][17][8];
    __shared__ unsigned sA[2][16 * STRIDE];
    __shared__ float sred[128];

    const int tid = threadIdx.x;
    const int l = tid & 15, grp = tid >> 4;
    const int lane = tid & 63, l4 = lane & 15, quad = lane >> 4;
    const int wv = tid >> 6;
    const int half = wv & 1;

    const bool convRole = (wv < 2);
    const bool sRole = HAS_S && (wv >= 2);
    short8 Bf[6];
    float bias0 = 0.f;
    if (convRole) {
#pragma unroll
        for (int s = 0; s < 5; ++s)
#pragma unroll
            for (int j = 0; j < 8; ++j)
                Bf[s][j] = (short)f2bf(g[(quad * 8 + j) * 160 + s * 32 + 16 * half + l4]);
#pragma unroll
        for (int j = 0; j < 8; ++j)
            Bf[5][j] = (short)f2bf(rootm[(quad * 8 + j) * 32 + 16 * half + l4]);
        bias0 = bm[16 * half + l4];
    } else if (sRole) {
#pragma unroll
        for (int j = 0; j < 8; ++j) {
            Bf[0][j] = (short)f2bf(gss[(quad * 8 + j) * 32 + 16 * half + l4]);
            Bf[1][j] = (short)f2bf(rootss[(quad * 8 + j) * 32 + 16 * half + l4]);
        }
        bias0 = bss[16 * half + l4];
    }

    float mm[15], im[15];
#pragma unroll
    for (int i = 0; i < 15; ++i) {
        mm[i] = mu_m[i];
        float s = sg_m[i];
        im[i] = 1.0f / (1e-15f + s * s);
    }
    float ms[3], is[3];
    if (HAS_S) {
#pragma unroll
        for (int i = 0; i < 3; ++i) {
            ms[i] = mu_s[i];
            float s = sg_s[i];
            is[i] = 1.0f / (1e-15f + s * s);
        }
    }

    float ps = 0.f, pq = 0.f;       // per-thread BN partials (role channel)

    // MFMA + epilogue for a completed tile in buffer `b`
    auto mfma_tile = [&](int b, int tileDone) {
        if (!(convRole || sRole)) return;
        const unsigned* sAb = sA[b];
        floatx4 C = {0.f, 0.f, 0.f, 0.f};
        if (convRole) {
#pragma unroll
            for (int s = 0; s < 6; ++s) {
                const int slot = (s < 5) ? s : KS;          // root slice last
                const uint4 av = *(const uint4*)(sAb + l4 * STRIDE + slot * 16 + quad * 4);
                const short8 A = *reinterpret_cast<const short8*>(&av);
                C = __builtin_amdgcn_mfma_f32_16x16x32_bf16(A, Bf[s], C, 0, 0, 0);
            }
        } else {
#pragma unroll
            for (int s = 0; s < 2; ++s) {
                const int slot = 5 + s;                     // shortcut agg, root
                const uint4 av = *(const uint4*)(sAb + l4 * STRIDE + slot * 16 + quad * 4);
                const short8 A = *reinterpret_cast<const short8*>(&av);
                C = __builtin_amdgcn_mfma_f32_16x16x32_bf16(A, Bf[s], C, 0, 0, 0);
            }
        }
        float* outp = convRole ? out_m : out_s;
#pragma unroll
        for (int r = 0; r < 4; ++r) {
            const int n = tileDone * 16 + quad * 4 + r;
            if (n < N) {
                const float v = C[r] + bias0;
                outp[(size_t)n * 32 + 16 * half + l4] = v;
                ps += v; pq += v * v;
            }
        }
    };

    int p = 0, prevTile = -1;

    for (int tile = blockIdx.x; tile < ntiles; tile += gridDim.x) {
        // ---- gather phase: dst = tile*16 + grp ----
        const int dst = tile * 16 + grp;
        float2 acc[KS];
#pragma unroll
        for (int k = 0; k < KS; ++k) acc[k] = make_float2(0.f, 0.f);

        int rp0 = 0, deg = 0;
        if (dst < N) { rp0 = row_ptr[dst]; deg = row_ptr[dst + 1] - rp0; }

        auto body = [&](int j) {
            const float4 a = *(const float4*)&wbuf[grp][j][0];
            const float4 b = *(const float4*)&wbuf[grp][j][4];
            const int sj = __float_as_int(a.x);
            const unsigned u = XB[(size_t)sj * 16 + l];
            const float x0 = bflo(u), x1 = bfhi(u);
            acc[0].x = fmaf(a.y, x0, acc[0].x); acc[0].y = fmaf(a.y, x1, acc[0].y);
            acc[1].x = fmaf(a.z, x0, acc[1].x); acc[1].y = fmaf(a.z, x1, acc[1].y);
            acc[2].x = fmaf(a.w, x0, acc[2].x); acc[2].y = fmaf(a.w, x1, acc[2].y);
            acc[3].x = fmaf(b.x, x0, acc[3].x); acc[3].y = fmaf(b.x, x1, acc[3].y);
            acc[4].x = fmaf(b.y, x0, acc[4].x); acc[4].y = fmaf(b.y, x1, acc[4].y);
            if (HAS_S) {
                acc[5].x = fmaf(b.z, x0, acc[5].x); acc[5].y = fmaf(b.z, x1, acc[5].y);
            }
        };

        for (int base = 0; base < deg; base += 16) {
            const int nj = min(16, deg - base);
            if (l < nj) {
                unsigned long long pq8 = payload[rp0 + base + l];
                const int src = (int)(pq8 & 0x1FFFFull);
                float p0 = ((int)((pq8 >> 26) & 0xFFF) + 0.5f) * DQ;
                float p1 = ((int)((pq8 >> 38) & 0xFFF) + 0.5f) * DQ;
                float p2 = ((int)((pq8 >> 50) & 0xFFF) + 0.5f) * DQ;
                float w[5], wS = 0.f;
#pragma unroll
                for (int k = 0; k < 5; ++k) {
                    float d0 = p0 - mm[k * 3 + 0];
                    float d1 = p1 - mm[k * 3 + 1];
                    float d2 = p2 - mm[k * 3 + 2];
                    float q = d0 * d0 * im[k * 3 + 0] + d1 * d1 * im[k * 3 + 1]
                            + d2 * d2 * im[k * 3 + 2];
                    w[k] = __expf(-0.5f * q);
                }
                if (HAS_S) {
                    float d0 = p0 - ms[0], d1 = p1 - ms[1], d2 = p2 - ms[2];
                    float q = d0 * d0 * is[0] + d1 * d1 * is[1] + d2 * d2 * is[2];
                    wS = __expf(-0.5f * q);
                }
                float4* wp = (float4*)&wbuf[grp][l][0];
                wp[0] = make_float4(__int_as_float(src), w[0], w[1], w[2]);
                wp[1] = make_float4(w[3], w[4], wS, 0.f);
            }
            int j = 0;
            for (; j + 3 < nj; j += 4) { body(j); body(j + 1); body(j + 2); body(j + 3); }
            for (; j < nj; ++j) body(j);
        }

        // ---- write A-tile to buffer p ----
        {
            unsigned* arow = sA[p] + grp * STRIDE;
            const float invd = 1.0f / fmaxf((float)deg, 1.0f);
            const bool ok = (dst < N);
#pragma unroll
            for (int k = 0; k < KS; ++k)
                arow[k * 16 + l] = ok ? pack_bf2(acc[k].x * invd, acc[k].y * invd) : 0u;
            arow[KS * 16 + l] = ok ? XB[(size_t)dst * 16 + l] : 0u;   // root slot
        }

        // ---- MFMA of PREVIOUS tile (buffer 1-p), overlaps slow gatherers ----
        if (prevTile >= 0) mfma_tile(1 - p, prevTile);

        __syncthreads();
        prevTile = tile;
        p ^= 1;
    }
    // drain: last tile's MFMA (its writes were barriered above)
    if (prevTile >= 0) mfma_tile(1 - p, prevTile);

    // ---- block-level BN stat reduction (once per block) ----
    if (tid < 128) sred[tid] = 0.f;
    __syncthreads();
    if (convRole) {
        atomicAdd(&sred[16 * half + l4], ps);
        atomicAdd(&sred[32 + 16 * half + l4], pq);
    } else if (sRole) {
        atomicAdd(&sred[64 + 16 * half + l4], ps);
        atomicAdd(&sred[96 + 16 * half + l4], pq);
    }
    __syncthreads();
    const int spread = (blockIdx.x & 7) * 64;
    if (tid < 64) atomicAdd(&stats_m[spread + tid], sred[tid]);
    else if (HAS_S && tid < 128) atomicAdd(&stats_s[spread + tid - 64], sred[tid]);
}

// ---- BN coefficients: two sets in one launch ------------------------------
__global__ void coef2_k(const float* __restrict__ stats1, const float* __restrict__ gam1,
                        const float* __restrict__ bet1, float* __restrict__ coef1,
                        const float* __restrict__ stats2, const float* __restrict__ gam2,
                        const float* __restrict__ bet2, float* __restrict__ coef2,
                        float invN)
{
    const int t = threadIdx.x;
    const int set = t >> 6;
    const int c = t & 63;
    if (c >= 32) return;
    const float* stats = set ? stats2 : stats1;
    const float* gam = set ? gam2 : gam1;
    const float* bet = set ? bet2 : bet1;
    float* coef = set ? coef2 : coef1;
    if (set && !stats) return;
    float s = 0.f, q = 0.f;
    for (int p = 0; p < 8; ++p) { s += stats[p * 64 + c]; q += stats[p * 64 + 32 + c]; }
    float m = s * invN;
    float v = fmaxf(q * invN - m * m, 0.f);
    float sc = gam[c] * rsqrtf(v + 1e-5f);
    coef[c] = sc;
    coef[32 + c] = bet[c] - m * sc;
}

// ---- final: out = elu(bn2(o2) + bns(os)) ----------------------------------
__global__ __launch_bounds__(256) void final_k(
    const float* __restrict__ o2, const float* __restrict__ os,
    const float* __restrict__ c2, const float* __restrict__ cs,
    float* __restrict__ out, int total)
{
    int idx = blockIdx.x * blockDim.x + threadIdx.x;
    if (idx >= total) return;
    int c = idx & 31;
    float v = o2[idx] * c2[c] + c2[32 + c] + os[idx] * cs[c] + cs[32 + c];
    out[idx] = ELU(v);
}

extern "C" void kernel_launch(void* const* d_in, const int* in_sizes, int n_in,
                              void* d_out, int out_size, void* d_ws, size_t ws_size,
                              hipStream_t stream)
{
    const float* x      = (const float*)d_in[0];
    const int*   ei     = (const int*)d_in[1];
    const float* attr   = (const float*)d_in[2];
    const float* g1     = (const float*)d_in[3];
    const float* mu1    = (const float*)d_in[4];
    const float* sig1   = (const float*)d_in[5];
    const float* root1  = (const float*)d_in[6];
    const float* b1     = (const float*)d_in[7];
    const float* gam1   = (const float*)d_in[8];
    const float* bet1   = (const float*)d_in[9];
    const float* g2     = (const float*)d_in[10];
    const float* mu2    = (const float*)d_in[11];
    const float* sig2   = (const float*)d_in[12];
    const float* root2  = (const float*)d_in[13];
    const float* b2     = (const float*)d_in[14];
    const float* gam2   = (const float*)d_in[15];
    const float* bet2   = (const float*)d_in[16];
    const float* gs     = (const float*)d_in[17];
    const float* mus    = (const float*)d_in[18];
    const float* sigs   = (const float*)d_in[19];
    const float* roots  = (const float*)d_in[20];
    const float* bs     = (const float*)d_in[21];
    const float* gams   = (const float*)d_in[22];
    const float* bets   = (const float*)d_in[23];

    const int N = in_sizes[0] / 32;
    const int E = in_sizes[1] / 2;
    const int total = N * 32;
    const int ntiles = (N + 15) / 16;
    const int NB = (N + 511) >> 9;                  // buckets (<=256 required)
    const int CAPc = ((((E + NB - 1) / NB) * 5) / 4 + 15) & ~15;

    char* ws = (char*)d_ws;
    size_t off = 0;
    auto carve = [&](size_t bytes) {
        void* p = ws + off;
        off = (off + bytes + 255) & ~(size_t)255;
        return p;
    };
    unsigned* XB   = (unsigned*)carve((size_t)N * 16 * 4);     // 6.4 MB
    float*  OUT1   = (float*)carve((size_t)N * 32 * 4);
    float*  OUT2   = (float*)carve((size_t)N * 32 * 4);
    float*  OUTS   = (float*)carve((size_t)N * 32 * 4);
    unsigned long long* PAY  = (unsigned long long*)carve((size_t)E * 8);          // 12.8 MB
    unsigned long long* PAY0 = (unsigned long long*)carve((size_t)NB * CAPc * 8);  // 16 MB
    int*    ROWP   = (int*)carve((size_t)(N + 1) * 4);
    int*    GCUR   = (int*)carve(256 * 4);                     // contiguous w/ STATS
    float*  STATS  = (float*)carve(3 * 512 * 4);               // 3 convs x [8][64]
    float*  COEF   = (float*)carve(3 * 64 * 4);
    float* stats1 = STATS, *stats2 = STATS + 512, *statsS = STATS + 1024;
    float* coef1 = COEF, *coef2 = COEF + 64, *coefS = COEF + 128;
    (void)ws_size; (void)n_in; (void)out_size;

    const float invN = 1.0f / (float)N;
    const int ew = (total + 255) / 256;
    const int epb = (N * 16 + 255) / 256;
    const int nfb = (E + CH - 1) / CH;
    const int gtb = ntiles < 1536 ? ntiles : 1536;  // 6 blocks/CU residency

    // GCUR (1 KB) and STATS (6 KB) are contiguous: single memset
    hipMemsetAsync(GCUR, 0, 256 * 4 + 3 * 512 * 4, stream);

    // CSR build (+ fused pass-A XB cast)
    binfill_k<<<nfb, 256, 0, stream>>>(ei, attr, GCUR, PAY0, x, XB, N * 16, E, NB, CAPc);
    scatter2_k<<<NB, 256, 0, stream>>>(PAY0, GCUR, ROWP, PAY, N, CAPc, NB);

    // pass A
    gt_k<true><<<gtb, 256, 0, stream>>>(XB, PAY, ROWP,
        mu1, sig1, mus, sigs, g1, root1, b1, gs, roots, bs,
        OUT1, OUTS, stats1, statsS, N, ntiles);
    coef2_k<<<1, 128, 0, stream>>>(stats1, gam1, bet1, coef1,
                                   statsS, gams, bets, coefS, invN);

    // pass B
    prep_hxb<<<epb, 256, 0, stream>>>(OUT1, coef1, XB, N);
    gt_k<false><<<gtb, 256, 0, stream>>>(XB, PAY, ROWP,
        mu2, sig2, nullptr, nullptr, g2, root2, b2, nullptr, nullptr, nullptr,
        OUT2, nullptr, stats2, nullptr, N, ntiles);
    coef2_k<<<1, 128, 0, stream>>>(stats2, gam2, bet2, coef2,
                                   nullptr, nullptr, nullptr, nullptr, invN);

    final_k<<<ew, 256, 0, stream>>>(OUT2, OUTS, coef2, coefS, (float*)d_out, total);
}

// Round 12
// 325.122 us; speedup vs baseline: 1.0080x; 1.0080x over previous
//
#include <hip/hip_runtime.h>
#include <hip/hip_bf16.h>
#include <math.h>

// ---------------------------------------------------------------------------
// ResidualBlock (PyG GMMConv/MoNet + BN train + ELU), v12.
//   Split gather/transform restored (v8 shape — fused gt_k lost 40% occupancy
//   to its LDS A-tile and ran 75-80 vs 48+12 split). Changes vs v8:
//   - gather: packed v_pk_fma_f32 accumulation (v2f + elementwise_fma);
//     no root slot staged (transform reads root A-slice from XB directly).
//   - binfill: CH=2048 (23 KB LDS -> 6 blocks/CU, was 3) + fused XB cast.
//   - scatter2: 512 threads/bucket, in-kernel bucket-base scan.
//   - coef launches merged (coef2_k); single memset for GCUR+STATS.
// ---------------------------------------------------------------------------

#define ELU(v) ((v) > 0.f ? (v) : (__expf(v) - 1.f))

using short8  = __attribute__((ext_vector_type(8))) short;
using floatx4 = __attribute__((ext_vector_type(4))) float;
using v2f     = __attribute__((ext_vector_type(2))) float;

__device__ inline ushort f2bf(float f) {
    __hip_bfloat16 h = __float2bfloat16(f);
    return *reinterpret_cast<ushort*>(&h);
}
__device__ inline float bflo(unsigned u) { return __uint_as_float(u << 16); }
__device__ inline float bfhi(unsigned u) { return __uint_as_float(u & 0xffff0000u); }
__device__ inline unsigned pack_bf2(float lo, float hi) {
    return ((unsigned)f2bf(hi) << 16) | (unsigned)f2bf(lo);
}

// ---- pass-B gather-source cast: XB = bf16(elu(bn1(out1))) -----------------
__global__ __launch_bounds__(256) void prep_hxb(
    const float* __restrict__ out1, const float* __restrict__ coef,
    unsigned* __restrict__ XB, int N)
{
    const int idx = blockIdx.x * blockDim.x + threadIdx.x;
    if (idx >= N * 16) return;
    const int l = idx & 15;
    const float2 p = ((const float2*)out1)[idx];
    const int c0 = 2 * l, c1 = 2 * l + 1;
    float v0 = p.x * coef[c0] + coef[32 + c0];
    float v1 = p.y * coef[c1] + coef[32 + c1];
    v0 = ELU(v0); v1 = ELU(v1);
    XB[idx] = pack_bf2(v0, v1);
}

// ---- CSR build, level 1: LDS-binned partition + fused XB cast -------------
#define CH 2048
__global__ __launch_bounds__(256) void binfill_k(
    const int* __restrict__ ei, const float* __restrict__ attr,
    int* __restrict__ gcur, unsigned long long* __restrict__ pay0,
    const float* __restrict__ x, unsigned* __restrict__ XB, int nxb,
    int E, int NB, int CAPc)
{
    __shared__ unsigned long long srec[CH];     // 16 KB
    __shared__ unsigned char sbin[CH];          // 2 KB
    __shared__ int cnt[256], offs[256], wcur[256], gbase[256], sc[256];

    const int t = threadIdx.x;
    const int e0 = blockIdx.x * CH;
    const int nrec = min(CH, E - e0);

    // fused pass-A XB cast (independent of partition work)
    for (int i = t; i < CH; i += 256) {
        const int idx = e0 + i;
        if (idx < nxb) {
            const float2 p = ((const float2*)x)[idx];
            XB[idx] = pack_bf2(p.x, p.y);
        }
    }

    cnt[t] = 0;
    __syncthreads();

    unsigned long long rec[8];
    int bin[8];
#pragma unroll
    for (int r = 0; r < 8; ++r) {
        const int e = e0 + r * 256 + t;
        bin[r] = -1;
        if (e < E) {
            const int s = ei[e], d = ei[E + e];
            const float a0 = attr[(size_t)e * 3 + 0];
            const float a1 = attr[(size_t)e * 3 + 1];
            const float a2 = attr[(size_t)e * 3 + 2];
            const unsigned q0 = (unsigned)min(max((int)(a0 * 4096.f), 0), 4095);
            const unsigned q1 = (unsigned)min(max((int)(a1 * 4096.f), 0), 4095);
            const unsigned q2 = (unsigned)min(max((int)(a2 * 4096.f), 0), 4095);
            rec[r] = (unsigned long long)(unsigned)s
                   | ((unsigned long long)(d & 511) << 17)
                   | ((unsigned long long)q0 << 26)
                   | ((unsigned long long)q1 << 38)
                   | ((unsigned long long)q2 << 50);
            bin[r] = d >> 9;
            atomicAdd(&cnt[bin[r]], 1);
        }
    }
    __syncthreads();

    const int v = cnt[t];
    sc[t] = v;
    __syncthreads();
    for (int o = 1; o < 256; o <<= 1) {
        const int xx = (t >= o) ? sc[t - o] : 0;
        __syncthreads();
        sc[t] += xx;
        __syncthreads();
    }
    offs[t] = sc[t] - v;
    wcur[t] = sc[t] - v;
    __syncthreads();

#pragma unroll
    for (int r = 0; r < 8; ++r) {
        if (bin[r] >= 0) {
            const int pos = atomicAdd(&wcur[bin[r]], 1);
            srec[pos] = rec[r];
            sbin[pos] = (unsigned char)bin[r];
        }
    }
    __syncthreads();

    if (t < NB && cnt[t] > 0) gbase[t] = atomicAdd(&gcur[t], cnt[t]);
    __syncthreads();

    for (int i = t; i < nrec; i += 256) {
        const int b = sbin[i];
        const int idx = gbase[b] + (i - offs[b]);
        if (idx < CAPc)
            pay0[(size_t)b * CAPc + idx] = srec[i];
    }
}

// ---- CSR build, level 2: bucket base + degree count + row_ptr + scatter ---
__global__ __launch_bounds__(512) void scatter2_k(
    const unsigned long long* __restrict__ pay0, const int* __restrict__ gcur,
    int* __restrict__ row_ptr, unsigned long long* __restrict__ pay,
    int N, int CAPc, int NB)
{
    const int b = blockIdx.x;
    const int t = threadIdx.x;
    const int d0 = b << 9;
    const int nd = min(512, N - d0);

    __shared__ int cnt[512];
    __shared__ int offs[512];
    __shared__ int sscan[512];
    __shared__ int ssum[512];

    // bucket base = sum of gcur[0..b)
    ssum[t] = (t < b && t < NB) ? gcur[t] : 0;
    cnt[t] = 0;
    __syncthreads();
    for (int o = 256; o > 0; o >>= 1) {
        if (t < o) ssum[t] += ssum[t + o];
        __syncthreads();
    }
    const int base = ssum[0];

    const int total = min(gcur[b], CAPc);
    const unsigned long long* src = pay0 + (size_t)b * CAPc;

    for (int i = t; i < total; i += 512) {
        const int dlo = (int)((src[i] >> 17) & 511);
        atomicAdd(&cnt[dlo], 1);
    }
    __syncthreads();

    // exclusive scan of cnt[0..511], 512-wide
    const int v = cnt[t];
    sscan[t] = v;
    __syncthreads();
    for (int o = 1; o < 512; o <<= 1) {
        const int xx = (t >= o) ? sscan[t - o] : 0;
        __syncthreads();
        sscan[t] += xx;
        __syncthreads();
    }
    offs[t] = sscan[t] - v;
    __syncthreads();
    const int btotal = sscan[511];

    if (t < nd) row_ptr[d0 + t] = base + offs[t];
    if (b == NB - 1 && t == 0) row_ptr[N] = base + btotal;

    cnt[t] = offs[t];
    __syncthreads();

    for (int i = t; i < total; i += 512) {
        const unsigned long long rec = src[i];
        const int dlo = (int)((rec >> 17) & 511);
        const int p = atomicAdd(&cnt[dlo], 1);
        pay[base + p] = rec;
    }
}

// ---- gather: AGGb slot k = (1/deg) * sum_e w_ek * x_bf16[src] -------------
// 16 lanes/dst; packed pk_fma accumulation; KS slots, no root slot.
template <bool HAS_S>
__global__ __launch_bounds__(256) void gather_k(
    const unsigned* __restrict__ XB,    // [n][16] dwords = 32 bf16 channels
    const unsigned long long* __restrict__ payload,
    const int* __restrict__ row_ptr,
    const float* __restrict__ mu_m, const float* __restrict__ sg_m,
    const float* __restrict__ mu_s, const float* __restrict__ sg_s,
    unsigned* __restrict__ AGGb,        // [n][KS*16] dwords (bf16 pairs)
    int N, int ntiles)
{
    constexpr int KS = HAS_S ? 6 : 5;
    constexpr float DQ = 1.0f / 4096.0f;

    float mm[15], im[15];
#pragma unroll
    for (int i = 0; i < 15; ++i) {
        mm[i] = mu_m[i];
        float s = sg_m[i];
        im[i] = 1.0f / (1e-15f + s * s);
    }
    float ms[3], is[3];
    if (HAS_S) {
#pragma unroll
        for (int i = 0; i < 3; ++i) {
            ms[i] = mu_s[i];
            float s = sg_s[i];
            is[i] = 1.0f / (1e-15f + s * s);
        }
    }

    const int l = threadIdx.x & 15;
    const int g = threadIdx.x >> 4;
    __shared__ float wbuf[16][17][8];

    for (int tile = blockIdx.x; tile < ntiles; tile += gridDim.x) {
        const int dst = tile * 16 + g;
        v2f acc[KS];
#pragma unroll
        for (int k = 0; k < KS; ++k) acc[k] = (v2f){0.f, 0.f};

        int rp0 = 0, deg = 0;
        if (dst < N) { rp0 = row_ptr[dst]; deg = row_ptr[dst + 1] - rp0; }

        auto body = [&](int j) {
            const float4 a = *(const float4*)&wbuf[g][j][0];
            const float4 b = *(const float4*)&wbuf[g][j][4];
            const int sj = __float_as_int(a.x);
            const unsigned u = XB[(size_t)sj * 16 + l];
            const v2f xv = {bflo(u), bfhi(u)};
            acc[0] = __builtin_elementwise_fma((v2f){a.y, a.y}, xv, acc[0]);
            acc[1] = __builtin_elementwise_fma((v2f){a.z, a.z}, xv, acc[1]);
            acc[2] = __builtin_elementwise_fma((v2f){a.w, a.w}, xv, acc[2]);
            acc[3] = __builtin_elementwise_fma((v2f){b.x, b.x}, xv, acc[3]);
            acc[4] = __builtin_elementwise_fma((v2f){b.y, b.y}, xv, acc[4]);
            if (HAS_S)
                acc[5] = __builtin_elementwise_fma((v2f){b.z, b.z}, xv, acc[5]);
        };

        for (int base = 0; base < deg; base += 16) {
            const int nj = min(16, deg - base);
            if (l < nj) {
                unsigned long long pq8 = payload[rp0 + base + l];
                const int src = (int)(pq8 & 0x1FFFFull);
                float p0 = ((int)((pq8 >> 26) & 0xFFF) + 0.5f) * DQ;
                float p1 = ((int)((pq8 >> 38) & 0xFFF) + 0.5f) * DQ;
                float p2 = ((int)((pq8 >> 50) & 0xFFF) + 0.5f) * DQ;
                float w[5], wS = 0.f;
#pragma unroll
                for (int k = 0; k < 5; ++k) {
                    float d0 = p0 - mm[k * 3 + 0];
                    float d1 = p1 - mm[k * 3 + 1];
                    float d2 = p2 - mm[k * 3 + 2];
                    float q = d0 * d0 * im[k * 3 + 0] + d1 * d1 * im[k * 3 + 1]
                            + d2 * d2 * im[k * 3 + 2];
                    w[k] = __expf(-0.5f * q);
                }
                if (HAS_S) {
                    float d0 = p0 - ms[0], d1 = p1 - ms[1], d2 = p2 - ms[2];
                    float q = d0 * d0 * is[0] + d1 * d1 * is[1] + d2 * d2 * is[2];
                    wS = __expf(-0.5f * q);
                }
                float4* wp = (float4*)&wbuf[g][l][0];
                wp[0] = make_float4(__int_as_float(src), w[0], w[1], w[2]);
                wp[1] = make_float4(w[3], w[4], wS, 0.f);
            }
            int j = 0;
            for (; j + 3 < nj; j += 4) { body(j); body(j + 1); body(j + 2); body(j + 3); }
            for (; j < nj; ++j) body(j);
        }

        if (dst < N) {
            const float invd = 1.0f / fmaxf((float)deg, 1.0f);
            unsigned* out = AGGb + (size_t)dst * (KS * 16) + l;
#pragma unroll
            for (int k = 0; k < KS; ++k)
                out[k * 16] = pack_bf2(acc[k][0] * invd, acc[k][1] * invd);
        }
    }
}

// ---- transform (MFMA): out = [agg | x] @ [G ; root] + bias; BN stats ------
// A slots 0..4 (conv agg) from AGGb; root A-slice read directly from XB.
// HAS_S: shortcut = AGGb slot 5 + XB root slice.
template <bool HAS_S>
__global__ __launch_bounds__(256) void transform_k(
    const unsigned* __restrict__ AGGb,  // [n][KS*16] dwords
    const unsigned* __restrict__ XBd,   // [n][16] dwords (root source)
    const float* __restrict__ g,        // [32][160]
    const float* __restrict__ rootm,    // [32][32]
    const float* __restrict__ bm,       // [32]
    const float* __restrict__ gss,      // [32][32] (HAS_S)
    const float* __restrict__ rootss,   // [32][32] (HAS_S)
    const float* __restrict__ bss,      // [32]     (HAS_S)
    float* __restrict__ out_m, float* __restrict__ out_s,
    float* __restrict__ stats_m, float* __restrict__ stats_s,
    int N)
{
    constexpr int KS = HAS_S ? 6 : 5;
    const int lane = threadIdx.x & 63;
    const int l4 = lane & 15, quad = lane >> 4;
    const int wv = threadIdx.x >> 6;

    short8 Bc[6][2];
#pragma unroll
    for (int s = 0; s < 5; ++s)
#pragma unroll
        for (int t = 0; t < 2; ++t)
#pragma unroll
            for (int j = 0; j < 8; ++j)
                Bc[s][t][j] = (short)f2bf(g[(quad * 8 + j) * 160 + s * 32 + 16 * t + l4]);
#pragma unroll
    for (int t = 0; t < 2; ++t)
#pragma unroll
        for (int j = 0; j < 8; ++j)
            Bc[5][t][j] = (short)f2bf(rootm[(quad * 8 + j) * 32 + 16 * t + l4]);

    short8 Bs2[2][2];
    if (HAS_S) {
#pragma unroll
        for (int t = 0; t < 2; ++t)
#pragma unroll
            for (int j = 0; j < 8; ++j) {
                Bs2[0][t][j] = (short)f2bf(gss[(quad * 8 + j) * 32 + 16 * t + l4]);
                Bs2[1][t][j] = (short)f2bf(rootss[(quad * 8 + j) * 32 + 16 * t + l4]);
            }
    }

    const float bm0 = bm[l4], bm1 = bm[16 + l4];
    const float bs0 = HAS_S ? bss[l4] : 0.f;
    const float bs1 = HAS_S ? bss[16 + l4] : 0.f;

    const int ngroups = (N + 15) >> 4;
    float ps0 = 0, pq0 = 0, ps1 = 0, pq1 = 0;
    float psS0 = 0, pqS0 = 0, psS1 = 0, pqS1 = 0;

    for (int grp = blockIdx.x * 4 + wv; grp < ngroups; grp += gridDim.x * 4) {
        const int node0 = grp * 16;
        const int myn = min(node0 + l4, N - 1);
        const unsigned* arow = AGGb + (size_t)myn * (KS * 16) + quad * 4;
        const uint4 rootA = *(const uint4*)(XBd + (size_t)myn * 16 + quad * 4);
        const short8 Ar = *reinterpret_cast<const short8*>(&rootA);

        floatx4 acc0 = {0.f, 0.f, 0.f, 0.f}, acc1 = {0.f, 0.f, 0.f, 0.f};
#pragma unroll
        for (int s = 0; s < 5; ++s) {
            const uint4 av = *(const uint4*)(arow + 16 * s);
            const short8 A = *reinterpret_cast<const short8*>(&av);
            acc0 = __builtin_amdgcn_mfma_f32_16x16x32_bf16(A, Bc[s][0], acc0, 0, 0, 0);
            acc1 = __builtin_amdgcn_mfma_f32_16x16x32_bf16(A, Bc[s][1], acc1, 0, 0, 0);
        }
        acc0 = __builtin_amdgcn_mfma_f32_16x16x32_bf16(Ar, Bc[5][0], acc0, 0, 0, 0);
        acc1 = __builtin_amdgcn_mfma_f32_16x16x32_bf16(Ar, Bc[5][1], acc1, 0, 0, 0);

        floatx4 accS0 = {0.f, 0.f, 0.f, 0.f}, accS1 = {0.f, 0.f, 0.f, 0.f};
        if (HAS_S) {
            const uint4 av = *(const uint4*)(arow + 16 * 5);
            const short8 A = *reinterpret_cast<const short8*>(&av);
            accS0 = __builtin_amdgcn_mfma_f32_16x16x32_bf16(A, Bs2[0][0], accS0, 0, 0, 0);
            accS1 = __builtin_amdgcn_mfma_f32_16x16x32_bf16(A, Bs2[0][1], accS1, 0, 0, 0);
            accS0 = __builtin_amdgcn_mfma_f32_16x16x32_bf16(Ar, Bs2[1][0], accS0, 0, 0, 0);
            accS1 = __builtin_amdgcn_mfma_f32_16x16x32_bf16(Ar, Bs2[1][1], accS1, 0, 0, 0);
        }

#pragma unroll
        for (int r = 0; r < 4; ++r) {
            const int n = node0 + quad * 4 + r;
            if (n < N) {
                float v0 = acc0[r] + bm0;
                float v1 = acc1[r] + bm1;
                out_m[(size_t)n * 32 + l4] = v0;
                out_m[(size_t)n * 32 + 16 + l4] = v1;
                ps0 += v0; pq0 += v0 * v0;
                ps1 += v1; pq1 += v1 * v1;
                if (HAS_S) {
                    float s0 = accS0[r] + bs0;
                    float s1 = accS1[r] + bs1;
                    out_s[(size_t)n * 32 + l4] = s0;
                    out_s[(size_t)n * 32 + 16 + l4] = s1;
                    psS0 += s0; pqS0 += s0 * s0;
                    psS1 += s1; pqS1 += s1 * s1;
                }
            }
        }
    }

    __shared__ float sred[64];
    const int tid = threadIdx.x;
    const int spread = (blockIdx.x & 7) * 64;
    {
        if (tid < 64) sred[tid] = 0.f;
        __syncthreads();
        atomicAdd(&sred[l4], ps0);       atomicAdd(&sred[16 + l4], ps1);
        atomicAdd(&sred[32 + l4], pq0);  atomicAdd(&sred[48 + l4], pq1);
        __syncthreads();
        if (tid < 64) atomicAdd(&stats_m[spread + tid], sred[tid]);
        __syncthreads();
    }
    if (HAS_S) {
        if (tid < 64) sred[tid] = 0.f;
        __syncthreads();
        atomicAdd(&sred[l4], psS0);      atomicAdd(&sred[16 + l4], psS1);
        atomicAdd(&sred[32 + l4], pqS0); atomicAdd(&sred[48 + l4], pqS1);
        __syncthreads();
        if (tid < 64) atomicAdd(&stats_s[spread + tid], sred[tid]);
    }
}

// ---- BN coefficients: two sets in one launch ------------------------------
__global__ void coef2_k(const float* __restrict__ stats1, const float* __restrict__ gam1,
                        const float* __restrict__ bet1, float* __restrict__ coef1,
                        const float* __restrict__ stats2, const float* __restrict__ gam2,
                        const float* __restrict__ bet2, float* __restrict__ coef2,
                        float invN)
{
    const int t = threadIdx.x;
    const int set = t >> 6;
    const int c = t & 63;
    if (c >= 32) return;
    const float* stats = set ? stats2 : stats1;
    const float* gam = set ? gam2 : gam1;
    const float* bet = set ? bet2 : bet1;
    float* coef = set ? coef2 : coef1;
    if (set && !stats) return;
    float s = 0.f, q = 0.f;
    for (int p = 0; p < 8; ++p) { s += stats[p * 64 + c]; q += stats[p * 64 + 32 + c]; }
    float m = s * invN;
    float v = fmaxf(q * invN - m * m, 0.f);
    float sc = gam[c] * rsqrtf(v + 1e-5f);
    coef[c] = sc;
    coef[32 + c] = bet[c] - m * sc;
}

// ---- final: out = elu(bn2(o2) + bns(os)) ----------------------------------
__global__ __launch_bounds__(256) void final_k(
    const float* __restrict__ o2, const float* __restrict__ os,
    const float* __restrict__ c2, const float* __restrict__ cs,
    float* __restrict__ out, int total)
{
    int idx = blockIdx.x * blockDim.x + threadIdx.x;
    if (idx >= total) return;
    int c = idx & 31;
    float v = o2[idx] * c2[c] + c2[32 + c] + os[idx] * cs[c] + cs[32 + c];
    out[idx] = ELU(v);
}

extern "C" void kernel_launch(void* const* d_in, const int* in_sizes, int n_in,
                              void* d_out, int out_size, void* d_ws, size_t ws_size,
                              hipStream_t stream)
{
    const float* x      = (const float*)d_in[0];
    const int*   ei     = (const int*)d_in[1];
    const float* attr   = (const float*)d_in[2];
    const float* g1     = (const float*)d_in[3];
    const float* mu1    = (const float*)d_in[4];
    const float* sig1   = (const float*)d_in[5];
    const float* root1  = (const float*)d_in[6];
    const float* b1     = (const float*)d_in[7];
    const float* gam1   = (const float*)d_in[8];
    const float* bet1   = (const float*)d_in[9];
    const float* g2     = (const float*)d_in[10];
    const float* mu2    = (const float*)d_in[11];
    const float* sig2   = (const float*)d_in[12];
    const float* root2  = (const float*)d_in[13];
    const float* b2     = (const float*)d_in[14];
    const float* gam2   = (const float*)d_in[15];
    const float* bet2   = (const float*)d_in[16];
    const float* gs     = (const float*)d_in[17];
    const float* mus    = (const float*)d_in[18];
    const float* sigs   = (const float*)d_in[19];
    const float* roots  = (const float*)d_in[20];
    const float* bs     = (const float*)d_in[21];
    const float* gams   = (const float*)d_in[22];
    const float* bets   = (const float*)d_in[23];

    const int N = in_sizes[0] / 32;
    const int E = in_sizes[1] / 2;
    const int total = N * 32;
    const int ntiles = (N + 15) / 16;
    const int NB = (N + 511) >> 9;                  // buckets (<=256 required)
    const int CAPc = ((((E + NB - 1) / NB) * 5) / 4 + 15) & ~15;

    char* ws = (char*)d_ws;
    size_t off = 0;
    auto carve = [&](size_t bytes) {
        void* p = ws + off;
        off = (off + bytes + 255) & ~(size_t)255;
        return p;
    };
    unsigned* XB   = (unsigned*)carve((size_t)N * 16 * 4);     // 6.4 MB
    unsigned* AGGb = (unsigned*)carve((size_t)N * 96 * 4);     // 38.4 MB (6 slots max)
    float*  OUT1   = (float*)carve((size_t)N * 32 * 4);
    float*  OUT2   = (float*)carve((size_t)N * 32 * 4);
    float*  OUTS   = (float*)carve((size_t)N * 32 * 4);
    unsigned long long* PAY  = (unsigned long long*)carve((size_t)E * 8);          // 12.8 MB
    unsigned long long* PAY0 = (unsigned long long*)carve((size_t)NB * CAPc * 8);  // 16 MB
    int*    ROWP   = (int*)carve((size_t)(N + 1) * 4);
    int*    GCUR   = (int*)carve(256 * 4);                     // contiguous w/ STATS
    float*  STATS  = (float*)carve(3 * 512 * 4);               // 3 convs x [8][64]
    float*  COEF   = (float*)carve(3 * 64 * 4);
    float* stats1 = STATS, *stats2 = STATS + 512, *statsS = STATS + 1024;
    float* coef1 = COEF, *coef2 = COEF + 64, *coefS = COEF + 128;
    (void)ws_size; (void)n_in; (void)out_size;

    const float invN = 1.0f / (float)N;
    const int ew = (total + 255) / 256;
    const int epb = (N * 16 + 255) / 256;
    const int nfb = (E + CH - 1) / CH;

    // GCUR (1 KB) + STATS (6 KB) contiguous: single memset
    hipMemsetAsync(GCUR, 0, 256 * 4 + 3 * 512 * 4, stream);

    // CSR build (+ fused pass-A XB cast)
    binfill_k<<<nfb, 256, 0, stream>>>(ei, attr, GCUR, PAY0, x, XB, N * 16, E, NB, CAPc);
    scatter2_k<<<NB, 512, 0, stream>>>(PAY0, GCUR, ROWP, PAY, N, CAPc, NB);

    // pass A
    gather_k<true><<<ntiles, 256, 0, stream>>>(XB, PAY, ROWP,
        mu1, sig1, mus, sigs, AGGb, N, ntiles);
    transform_k<true><<<1024, 256, 0, stream>>>(AGGb, XB, g1, root1, b1,
        gs, roots, bs, OUT1, OUTS, stats1, statsS, N);
    coef2_k<<<1, 128, 0, stream>>>(stats1, gam1, bet1, coef1,
                                   statsS, gams, bets, coefS, invN);

    // pass B
    prep_hxb<<<epb, 256, 0, stream>>>(OUT1, coef1, XB, N);
    gather_k<false><<<ntiles, 256, 0, stream>>>(XB, PAY, ROWP,
        mu2, sig2, nullptr, nullptr, AGGb, N, ntiles);
    transform_k<false><<<1024, 256, 0, stream>>>(AGGb, XB, g2, root2, b2,
        nullptr, nullptr, nullptr, OUT2, nullptr, stats2, nullptr, N);
    coef2_k<<<1, 128, 0, stream>>>(stats2, gam2, bet2, coef2,
                                   nullptr, nullptr, nullptr, nullptr, invN);

    final_k<<<ew, 256, 0, stream>>>(OUT2, OUTS, coef2, coefS, (float*)d_out, total);
}